// Round 4
// baseline (226.400 us; speedup 1.0000x reference)
//
#include <hip/hip_runtime.h>
#include <stdint.h>

// NormalComponentReconstructionLoss: mean_n || r - H (H^T r) ||^2
//   r = rec - pts (D=3), H = frame[n] in R^{3x2}. 192 MB read, memory-bound.
// R2 (AoS f4, vgpr32) and R3 (global_load_lds + vmcnt0 drain) both stuck at
// 2.6 TB/s for DIFFERENT reasons (request-pass inflation; LDS-DMA concurrency).
// R4: reg-staged transpose — lane-contiguous f4 loads into VGPRs,
// ds_write_b128 to wave-private LDS, per-point LDS reads, 1-slice-deep
// software pipeline (prefetch issued before stage+compute of current slice).

#define THREADS 256
#define NWAVES  (THREADS / 64)
#define BLOCKS  768                 // 3 blocks/CU (48KB LDS each), 12 waves/CU
#define WAVE_LDS 12288              // 256 points * 48 B per wave

// issue the 12 lane-contiguous float4 loads of slice S into named regs
#define ISSUE(S, p0,p1,p2,q0,q1,q2,f0,f1,f2,f3,f4v,f5) do {                  \
    const float4* Pg_ = P4 + (size_t)(S) * 192 + lane;                       \
    const float4* Rg_ = R4 + (size_t)(S) * 192 + lane;                       \
    const float4* Fg_ = F4 + (size_t)(S) * 384 + lane;                       \
    p0 = Pg_[0]; p1 = Pg_[64]; p2 = Pg_[128];                                \
    q0 = Rg_[0]; q1 = Rg_[64]; q2 = Rg_[128];                                \
    f0 = Fg_[0]; f1 = Fg_[64]; f2 = Fg_[128];                                \
    f3 = Fg_[192]; f4v = Fg_[256]; f5 = Fg_[320];                            \
} while (0)

// stage 12 regs into wave-private LDS (lane-contiguous ds_write_b128)
#define STAGE(p0,p1,p2,q0,q1,q2,f0,f1,f2,f3,f4v,f5) do {                     \
    float4* W_ = (float4*)(wbase) + lane;                                    \
    W_[0*64] = p0; W_[1*64] = p1; W_[2*64]  = p2;                            \
    W_[3*64] = q0; W_[4*64] = q1; W_[5*64]  = q2;                            \
    W_[6*64] = f0; W_[7*64] = f1; W_[8*64]  = f2;                            \
    W_[9*64] = f3; W_[10*64] = f4v; W_[11*64] = f5;                          \
} while (0)

// keep prefetch regs alive past the compute phase (blocks scheduler sinking)
#define KEEP(p0,p1,p2,q0,q1,q2,f0,f1,f2,f3,f4v,f5)                           \
    asm volatile("" :: "v"(p0.x), "v"(p1.x), "v"(p2.x), "v"(q0.x),           \
                       "v"(q1.x), "v"(q2.x), "v"(f0.x), "v"(f1.x),           \
                       "v"(f2.x), "v"(f3.x), "v"(f4v.x), "v"(f5.x))

__global__ __launch_bounds__(THREADS, 4) void ncrl_partial(
    const float* __restrict__ pts,
    const float* __restrict__ rec,
    const float* __restrict__ frame,
    float* __restrict__ partial,
    int nSlices)                    // 256-point slices
{
    __shared__ char stage[WAVE_LDS * NWAVES];   // 48 KB, disjoint per wave
    __shared__ float wsum[NWAVES];

    const int lane = threadIdx.x & 63;
    const int wv   = threadIdx.x >> 6;
    char* wbase = stage + wv * WAVE_LDS;
    const float* Lp = (const float*)(wbase);            // 768 f  pts
    const float* Lr = (const float*)(wbase + 3072);     // 768 f  rec
    const float* Lf = (const float*)(wbase + 6144);     // 1536 f frame

    const float4* P4 = (const float4*)pts;
    const float4* R4 = (const float4*)rec;
    const float4* F4 = (const float4*)frame;

    const int gw0      = blockIdx.x * NWAVES + wv;
    const int gwStride = gridDim.x * NWAVES;

    float4 A0, A1, A2, A3, A4, A5, A6, A7, A8, A9, A10, A11;  // slice s
    float4 B0, B1, B2, B3, B4, B5, B6, B7, B8, B9, B10, B11;  // slice s+str

    float acc = 0.0f;

#define COMPUTE() do {                                                        \
    _Pragma("unroll")                                                         \
    for (int k = 0; k < 4; ++k) {                                             \
        const int p = k * 64 + lane;                                          \
        const float a0 = Lp[3*p], a1 = Lp[3*p+1], a2 = Lp[3*p+2];             \
        const float b0 = Lr[3*p], b1 = Lr[3*p+1], b2 = Lr[3*p+2];             \
        const float2 h0 = *(const float2*)(Lf + 6*p);                         \
        const float2 h1 = *(const float2*)(Lf + 6*p + 2);                     \
        const float2 h2 = *(const float2*)(Lf + 6*p + 4);                     \
        const float r0 = b0 - a0, r1 = b1 - a1, r2 = b2 - a2;                 \
        const float c0 = h0.x*r0 + h1.x*r1 + h2.x*r2;                         \
        const float c1 = h0.y*r0 + h1.y*r1 + h2.y*r2;                         \
        const float d0 = r0 - (h0.x*c0 + h0.y*c1);                            \
        const float d1 = r1 - (h1.x*c0 + h1.y*c1);                            \
        const float d2 = r2 - (h2.x*c0 + h2.y*c1);                            \
        acc += d0*d0 + d1*d1 + d2*d2;                                         \
    }                                                                         \
} while (0)

    int s = gw0;
    if (s < nSlices)
        ISSUE(s, A0,A1,A2,A3,A4,A5,A6,A7,A8,A9,A10,A11);

    while (s < nSlices) {
        // ---- half 1: prefetch into B, stage+compute A ----
        {
            const int snext = s + gwStride;
            if (snext < nSlices)
                ISSUE(snext, B0,B1,B2,B3,B4,B5,B6,B7,B8,B9,B10,B11);
            STAGE(A0,A1,A2,A3,A4,A5,A6,A7,A8,A9,A10,A11);  // waits vmcnt(A)
            COMPUTE();
            s = snext;
            if (s >= nSlices) break;
            KEEP(B0,B1,B2,B3,B4,B5,B6,B7,B8,B9,B10,B11);
        }
        // ---- half 2: prefetch into A, stage+compute B ----
        {
            const int snext = s + gwStride;
            if (snext < nSlices)
                ISSUE(snext, A0,A1,A2,A3,A4,A5,A6,A7,A8,A9,A10,A11);
            STAGE(B0,B1,B2,B3,B4,B5,B6,B7,B8,B9,B10,B11);
            COMPUTE();
            s = snext;
            if (s >= nSlices) break;
            KEEP(A0,A1,A2,A3,A4,A5,A6,A7,A8,A9,A10,A11);
        }
    }

    // wave-64 butterfly reduce
#pragma unroll
    for (int off = 32; off > 0; off >>= 1)
        acc += __shfl_down(acc, off, 64);

    if (lane == 0) wsum[wv] = acc;
    __syncthreads();
    if (threadIdx.x == 0) {
        float ssum = 0.0f;
#pragma unroll
        for (int w = 0; w < NWAVES; ++w) ssum += wsum[w];
        partial[blockIdx.x] = ssum;
    }
}

__global__ __launch_bounds__(THREADS) void ncrl_finalize(
    const float* __restrict__ partial,
    const float* __restrict__ pts,
    const float* __restrict__ rec,
    const float* __restrict__ frame,
    float* __restrict__ out,
    int nPartial, int nTailStart, int nPoints)
{
    double acc = 0.0;
    for (int i = threadIdx.x; i < nPartial; i += THREADS)
        acc += (double)partial[i];

    // scalar tail (N % 256), empty for N=4M
    if (threadIdx.x == 0) {
        for (int n = nTailStart; n < nPoints; ++n) {
            const float r0 = rec[3*n+0] - pts[3*n+0];
            const float r1 = rec[3*n+1] - pts[3*n+1];
            const float r2 = rec[3*n+2] - pts[3*n+2];
            const float H00 = frame[6*n+0], H01 = frame[6*n+1];
            const float H10 = frame[6*n+2], H11 = frame[6*n+3];
            const float H20 = frame[6*n+4], H21 = frame[6*n+5];
            const float c0 = H00*r0 + H10*r1 + H20*r2;
            const float c1 = H01*r0 + H11*r1 + H21*r2;
            const float d0 = r0 - (H00*c0 + H01*c1);
            const float d1 = r1 - (H10*c0 + H11*c1);
            const float d2 = r2 - (H20*c0 + H21*c1);
            acc += (double)(d0*d0 + d1*d1 + d2*d2);
        }
    }

#pragma unroll
    for (int off = 32; off > 0; off >>= 1)
        acc += __shfl_down(acc, off, 64);

    __shared__ double dsum[NWAVES];
    const int lane = threadIdx.x & 63;
    const int wv   = threadIdx.x >> 6;
    if (lane == 0) dsum[wv] = acc;
    __syncthreads();
    if (threadIdx.x == 0) {
        double total = 0.0;
#pragma unroll
        for (int w = 0; w < NWAVES; ++w) total += dsum[w];
        out[0] = (float)(total / (double)nPoints);
    }
}

extern "C" void kernel_launch(void* const* d_in, const int* in_sizes, int n_in,
                              void* d_out, int out_size, void* d_ws, size_t ws_size,
                              hipStream_t stream) {
    const float* pts   = (const float*)d_in[0];   // [N,3]
    const float* rec   = (const float*)d_in[1];   // [N,3]
    const float* frame = (const float*)d_in[2];   // [N,3,2]
    float* out = (float*)d_out;

    const int N       = in_sizes[0] / 3;
    const int nSlices = N / 256;          // 15625 for N=4M, exact
    const int tail    = nSlices * 256;

    float* partial = (float*)d_ws;        // BLOCKS floats, all written every launch

    ncrl_partial<<<BLOCKS, THREADS, 0, stream>>>(pts, rec, frame, partial, nSlices);
    ncrl_finalize<<<1, THREADS, 0, stream>>>(partial, pts, rec, frame, out,
                                             BLOCKS, tail, N);
}

// Round 7
// 209.566 us; speedup vs baseline: 1.0803x; 1.0803x over previous
//
#include <hip/hip_runtime.h>
#include <stdint.h>

// NormalComponentReconstructionLoss: mean_n || r - H (H^T r) ||^2
//   r = rec - pts (D=3), H = frame[n] in R^{3x2}. 192 MB read, memory-bound.
// History: R2 AoS f4 (VGPR=32, shallow pipeline) 73us; R3 global_load_lds +
// vmcnt(0) drain 73us; R4 double-buffered reg-staging SPILLED (WRITE 133MB,
// 93us) but proved ~4.9 TB/s vmem throughput with deep issue.
// R5: single rotating reg buffer (12 x float4 = 48 VGPR): STAGE(s) ->
// ISSUE(s+1) same regs -> sched_barrier -> COMPUTE(s). Loads of s+1 in
// flight across compute; no spills; 12 waves/CU.

#define THREADS 256
#define NWAVES  (THREADS / 64)
#define BLOCKS  768                 // 3 blocks/CU (48KB LDS each), 12 waves/CU
#define WAVE_LDS 12288              // 256 points * 48 B per wave

// issue the 12 lane-contiguous float4 loads of slice S into the A regs
#define ISSUE(S) do {                                                        \
    const float4* Pg_ = P4 + (size_t)(S) * 192 + lane;                       \
    const float4* Rg_ = R4 + (size_t)(S) * 192 + lane;                       \
    const float4* Fg_ = F4 + (size_t)(S) * 384 + lane;                       \
    A0 = Pg_[0];   A1 = Pg_[64];  A2  = Pg_[128];                            \
    A3 = Rg_[0];   A4 = Rg_[64];  A5  = Rg_[128];                            \
    A6 = Fg_[0];   A7 = Fg_[64];  A8  = Fg_[128];                            \
    A9 = Fg_[192]; A10 = Fg_[256]; A11 = Fg_[320];                           \
} while (0)

// stage the 12 regs into wave-private LDS (lane-contiguous ds_write_b128;
// 16B/lane stride = 2-way bank alias on wave64 = time-free per m136)
#define STAGE() do {                                                         \
    float4* W_ = (float4*)(wbase) + lane;                                    \
    W_[0*64] = A0; W_[1*64] = A1; W_[2*64]  = A2;                            \
    W_[3*64] = A3; W_[4*64] = A4; W_[5*64]  = A5;                            \
    W_[6*64] = A6; W_[7*64] = A7; W_[8*64]  = A8;                            \
    W_[9*64] = A9; W_[10*64] = A10; W_[11*64] = A11;                         \
} while (0)

#define COMPUTE() do {                                                        \
    _Pragma("unroll")                                                         \
    for (int k = 0; k < 4; ++k) {                                             \
        const int p = k * 64 + lane;                                          \
        const float a0 = Lp[3*p], a1 = Lp[3*p+1], a2 = Lp[3*p+2];             \
        const float b0 = Lr[3*p], b1 = Lr[3*p+1], b2 = Lr[3*p+2];             \
        const float2 h0 = *(const float2*)(Lf + 6*p);                         \
        const float2 h1 = *(const float2*)(Lf + 6*p + 2);                     \
        const float2 h2 = *(const float2*)(Lf + 6*p + 4);                     \
        const float r0 = b0 - a0, r1 = b1 - a1, r2 = b2 - a2;                 \
        const float c0 = h0.x*r0 + h1.x*r1 + h2.x*r2;                         \
        const float c1 = h0.y*r0 + h1.y*r1 + h2.y*r2;                         \
        const float d0 = r0 - (h0.x*c0 + h0.y*c1);                            \
        const float d1 = r1 - (h1.x*c0 + h1.y*c1);                            \
        const float d2 = r2 - (h2.x*c0 + h2.y*c1);                            \
        acc += d0*d0 + d1*d1 + d2*d2;                                         \
    }                                                                         \
} while (0)

__global__ __launch_bounds__(THREADS) void ncrl_partial(
    const float* __restrict__ pts,
    const float* __restrict__ rec,
    const float* __restrict__ frame,
    float* __restrict__ partial,
    int nSlices)                    // 256-point slices
{
    __shared__ char smem[WAVE_LDS * NWAVES];   // 48 KB, disjoint per wave
    __shared__ float wsum[NWAVES];

    const int lane = threadIdx.x & 63;
    const int wv   = threadIdx.x >> 6;
    char* wbase = smem + wv * WAVE_LDS;
    const float* Lp = (const float*)(wbase);            // 768 f  pts
    const float* Lr = (const float*)(wbase + 3072);     // 768 f  rec
    const float* Lf = (const float*)(wbase + 6144);     // 1536 f frame

    const float4* P4 = (const float4*)pts;
    const float4* R4 = (const float4*)rec;
    const float4* F4 = (const float4*)frame;

    const int gw0      = blockIdx.x * NWAVES + wv;
    const int gwStride = gridDim.x * NWAVES;

    float4 A0, A1, A2, A3, A4, A5, A6, A7, A8, A9, A10, A11;
    float acc = 0.0f;

    int s = gw0;
    if (s < nSlices) {
        ISSUE(s);                               // prologue load
        while (true) {
            STAGE();                            // vmcnt wait + ds_write (consumes A)
            const int snext = s + gwStride;     // wave-uniform branch
            if (snext < nSlices)
                ISSUE(snext);                   // refill A; in flight across compute
            __builtin_amdgcn_sched_barrier(0);  // keep compute below the issue
            COMPUTE();                          // reads LDS (lgkmcnt by compiler)
            if (snext >= nSlices) break;
            s = snext;
        }
    }

    // wave-64 butterfly reduce
#pragma unroll
    for (int off = 32; off > 0; off >>= 1)
        acc += __shfl_down(acc, off, 64);

    if (lane == 0) wsum[wv] = acc;
    __syncthreads();
    if (threadIdx.x == 0) {
        float ssum = 0.0f;
#pragma unroll
        for (int w = 0; w < NWAVES; ++w) ssum += wsum[w];
        partial[blockIdx.x] = ssum;
    }
}

__global__ __launch_bounds__(THREADS) void ncrl_finalize(
    const float* __restrict__ partial,
    const float* __restrict__ pts,
    const float* __restrict__ rec,
    const float* __restrict__ frame,
    float* __restrict__ out,
    int nPartial, int nTailStart, int nPoints)
{
    double acc = 0.0;
    for (int i = threadIdx.x; i < nPartial; i += THREADS)
        acc += (double)partial[i];

    // scalar tail (N % 256), empty for N=4M
    if (threadIdx.x == 0) {
        for (int n = nTailStart; n < nPoints; ++n) {
            const float r0 = rec[3*n+0] - pts[3*n+0];
            const float r1 = rec[3*n+1] - pts[3*n+1];
            const float r2 = rec[3*n+2] - pts[3*n+2];
            const float H00 = frame[6*n+0], H01 = frame[6*n+1];
            const float H10 = frame[6*n+2], H11 = frame[6*n+3];
            const float H20 = frame[6*n+4], H21 = frame[6*n+5];
            const float c0 = H00*r0 + H10*r1 + H20*r2;
            const float c1 = H01*r0 + H11*r1 + H21*r2;
            const float d0 = r0 - (H00*c0 + H01*c1);
            const float d1 = r1 - (H10*c0 + H11*c1);
            const float d2 = r2 - (H20*c0 + H21*c1);
            acc += (double)(d0*d0 + d1*d1 + d2*d2);
        }
    }

#pragma unroll
    for (int off = 32; off > 0; off >>= 1)
        acc += __shfl_down(acc, off, 64);

    __shared__ double dsum[NWAVES];
    const int lane = threadIdx.x & 63;
    const int wv   = threadIdx.x >> 6;
    if (lane == 0) dsum[wv] = acc;
    __syncthreads();
    if (threadIdx.x == 0) {
        double total = 0.0;
#pragma unroll
        for (int w = 0; w < NWAVES; ++w) total += dsum[w];
        out[0] = (float)(total / (double)nPoints);
    }
}

extern "C" void kernel_launch(void* const* d_in, const int* in_sizes, int n_in,
                              void* d_out, int out_size, void* d_ws, size_t ws_size,
                              hipStream_t stream) {
    const float* pts   = (const float*)d_in[0];   // [N,3]
    const float* rec   = (const float*)d_in[1];   // [N,3]
    const float* frame = (const float*)d_in[2];   // [N,3,2]
    float* out = (float*)d_out;

    const int N       = in_sizes[0] / 3;
    const int nSlices = N / 256;          // 15625 for N=4M, exact
    const int tail    = nSlices * 256;

    float* partial = (float*)d_ws;        // BLOCKS floats, all written every launch

    ncrl_partial<<<BLOCKS, THREADS, 0, stream>>>(pts, rec, frame, partial, nSlices);
    ncrl_finalize<<<1, THREADS, 0, stream>>>(partial, pts, rec, frame, out,
                                             BLOCKS, tail, N);
}

// Round 10
// 209.539 us; speedup vs baseline: 1.0805x; 1.0001x over previous
//
#include <hip/hip_runtime.h>
#include <stdint.h>

// NormalComponentReconstructionLoss: mean_n || r - H (H^T r) ||^2
//   r = rec - pts (D=3), H = frame[n] in R^{3x2}. 192 MB read, memory-bound.
// History: R2 (AoS f4, VGPR=32) / R3 (global_load_lds) / R5 (pipelined
// reg-staging, no spill) ALL = 73 us = 2.6 TB/s. R4 (spilling) pushed 3.1 TB/s
// HBM at same occupancy -> pipes fine, input stream latency-starved.
// Saturation needs only 10.25 B/cy/CU, so coalescing inflation is irrelevant;
// wave-level concurrency is the lever. R8: NO LDS, direct in-register compute,
// 24 waves/CU (VGPR<=85 via launch_bounds), 12 float4 in flight per thread.

#define THREADS 256
#define NWAVES  (THREADS / 64)
#define BLOCKS  1536                // 6 blocks/CU, 24 waves/CU

// one point's worth of projection math, all operands scalar registers
#define POINT(pa0,pa1,pa2, pb0,pb1,pb2, H00,H01,H10,H11,H20,H21) do {        \
    const float r0 = (pb0) - (pa0);                                          \
    const float r1 = (pb1) - (pa1);                                          \
    const float r2 = (pb2) - (pa2);                                          \
    const float c0 = (H00)*r0 + (H10)*r1 + (H20)*r2;                         \
    const float c1 = (H01)*r0 + (H11)*r1 + (H21)*r2;                         \
    const float d0 = r0 - ((H00)*c0 + (H01)*c1);                             \
    const float d1 = r1 - ((H10)*c0 + (H11)*c1);                             \
    const float d2 = r2 - ((H20)*c0 + (H21)*c1);                             \
    acc += d0*d0 + d1*d1 + d2*d2;                                            \
} while (0)

__global__ __launch_bounds__(THREADS, 6) void ncrl_partial(
    const float* __restrict__ pts,
    const float* __restrict__ rec,
    const float* __restrict__ frame,
    float* __restrict__ partial,
    int nGroups)                    // 4-point groups
{
    const float4* __restrict__ P4 = (const float4*)pts;
    const float4* __restrict__ R4 = (const float4*)rec;
    const float4* __restrict__ F4 = (const float4*)frame;

    float acc = 0.0f;
    const int stride = gridDim.x * blockDim.x;
    for (int g = blockIdx.x * blockDim.x + threadIdx.x; g < nGroups; g += stride) {
        // 12 independent float4 loads — all issued before first use
        const float4 a0 = P4[3*(size_t)g + 0];
        const float4 a1 = P4[3*(size_t)g + 1];
        const float4 a2 = P4[3*(size_t)g + 2];
        const float4 b0 = R4[3*(size_t)g + 0];
        const float4 b1 = R4[3*(size_t)g + 1];
        const float4 b2 = R4[3*(size_t)g + 2];
        const float4 h0 = F4[6*(size_t)g + 0];
        const float4 h1 = F4[6*(size_t)g + 1];
        const float4 h2 = F4[6*(size_t)g + 2];
        const float4 h3 = F4[6*(size_t)g + 3];
        const float4 h4 = F4[6*(size_t)g + 4];
        const float4 h5 = F4[6*(size_t)g + 5];

        // 4 points, fully static component extraction (no arrays -> no scratch)
        POINT(a0.x,a0.y,a0.z,  b0.x,b0.y,b0.z,  h0.x,h0.y,h0.z,h0.w,h1.x,h1.y);
        POINT(a0.w,a1.x,a1.y,  b0.w,b1.x,b1.y,  h1.z,h1.w,h2.x,h2.y,h2.z,h2.w);
        POINT(a1.z,a1.w,a2.x,  b1.z,b1.w,b2.x,  h3.x,h3.y,h3.z,h3.w,h4.x,h4.y);
        POINT(a2.y,a2.z,a2.w,  b2.y,b2.z,b2.w,  h4.z,h4.w,h5.x,h5.y,h5.z,h5.w);
    }

    // wave-64 butterfly reduce
#pragma unroll
    for (int off = 32; off > 0; off >>= 1)
        acc += __shfl_down(acc, off, 64);

    __shared__ float wsum[NWAVES];
    const int lane = threadIdx.x & 63;
    const int wv   = threadIdx.x >> 6;
    if (lane == 0) wsum[wv] = acc;
    __syncthreads();
    if (threadIdx.x == 0) {
        float ssum = 0.0f;
#pragma unroll
        for (int w = 0; w < NWAVES; ++w) ssum += wsum[w];
        partial[blockIdx.x] = ssum;
    }
}

__global__ __launch_bounds__(THREADS) void ncrl_finalize(
    const float* __restrict__ partial,
    const float* __restrict__ pts,
    const float* __restrict__ rec,
    const float* __restrict__ frame,
    float* __restrict__ out,
    int nPartial, int nTailStart, int nPoints)
{
    double acc = 0.0;
    for (int i = threadIdx.x; i < nPartial; i += THREADS)
        acc += (double)partial[i];

    // scalar tail (N % 4), empty for N=4M
    if (threadIdx.x == 0) {
        for (int n = nTailStart; n < nPoints; ++n) {
            const float r0 = rec[3*n+0] - pts[3*n+0];
            const float r1 = rec[3*n+1] - pts[3*n+1];
            const float r2 = rec[3*n+2] - pts[3*n+2];
            const float H00 = frame[6*n+0], H01 = frame[6*n+1];
            const float H10 = frame[6*n+2], H11 = frame[6*n+3];
            const float H20 = frame[6*n+4], H21 = frame[6*n+5];
            const float c0 = H00*r0 + H10*r1 + H20*r2;
            const float c1 = H01*r0 + H11*r1 + H21*r2;
            const float d0 = r0 - (H00*c0 + H01*c1);
            const float d1 = r1 - (H10*c0 + H11*c1);
            const float d2 = r2 - (H20*c0 + H21*c1);
            acc += (double)(d0*d0 + d1*d1 + d2*d2);
        }
    }

#pragma unroll
    for (int off = 32; off > 0; off >>= 1)
        acc += __shfl_down(acc, off, 64);

    __shared__ double dsum[NWAVES];
    const int lane = threadIdx.x & 63;
    const int wv   = threadIdx.x >> 6;
    if (lane == 0) dsum[wv] = acc;
    __syncthreads();
    if (threadIdx.x == 0) {
        double total = 0.0;
#pragma unroll
        for (int w = 0; w < NWAVES; ++w) total += dsum[w];
        out[0] = (float)(total / (double)nPoints);
    }
}

extern "C" void kernel_launch(void* const* d_in, const int* in_sizes, int n_in,
                              void* d_out, int out_size, void* d_ws, size_t ws_size,
                              hipStream_t stream) {
    const float* pts   = (const float*)d_in[0];   // [N,3]
    const float* rec   = (const float*)d_in[1];   // [N,3]
    const float* frame = (const float*)d_in[2];   // [N,3,2]
    float* out = (float*)d_out;

    const int N       = in_sizes[0] / 3;
    const int nGroups = N / 4;            // 1,000,000 for N=4M, exact
    const int tail    = nGroups * 4;

    float* partial = (float*)d_ws;        // BLOCKS floats, all written every launch

    ncrl_partial<<<BLOCKS, THREADS, 0, stream>>>(pts, rec, frame, partial, nGroups);
    ncrl_finalize<<<1, THREADS, 0, stream>>>(partial, pts, rec, frame, out,
                                             BLOCKS, tail, N);
}